// Round 12
// baseline (736.551 us; speedup 1.0000x reference)
//
#include <hip/hip_runtime.h>
#include <hip/hip_bf16.h>

typedef unsigned short u16;
typedef unsigned int u32;
typedef __attribute__((ext_vector_type(8))) short bf16x8;
typedef __attribute__((ext_vector_type(4))) float f32x4;

#define SEQ 2048
#define DM 1024
#define NH 16
#define DKK 64
#define NB 2
#define NBLK 512

__device__ __forceinline__ u16 f2bf(float f) {
  union { float f; u32 u; } x; x.f = f;
  u32 r = x.u + 0x7FFFu + ((x.u >> 16) & 1u);
  return (u16)(r >> 16);
}

__device__ __forceinline__ void gl_lds16(const void* g, void* l) {
  __builtin_amdgcn_global_load_lds(
      (const __attribute__((address_space(1))) u32*)g,
      (__attribute__((address_space(3))) u32*)l, 16, 0, 0);
}

#define MFMA16(a, b, c) __builtin_amdgcn_mfma_f32_16x16x32_bf16(a, b, c, 0, 0, 0)
#define VMCNT0() asm volatile("s_waitcnt vmcnt(0)" ::: "memory")
#define SCHEDB() __builtin_amdgcn_sched_barrier(0)

// Software grid barrier: all NBLK blocks are co-resident by construction
// (launch_bounds(256,2) -> VGPR<=256 -> 2 blocks/CU; LDS 40KB -> 4/CU;
// 2*256CU = 512 = grid).  Device-scope atomics + threadfence for cross-XCD
// visibility (G16 recipe).  Counters zeroed per call via hipMemsetAsync.
__device__ __forceinline__ void gbar(int* cnt, int idx) {
  __syncthreads();
  if (threadIdx.x == 0) {
    __threadfence();
    __hip_atomic_fetch_add(&cnt[idx], 1, __ATOMIC_RELEASE,
                           __HIP_MEMORY_SCOPE_AGENT);
    while (__hip_atomic_load(&cnt[idx], __ATOMIC_ACQUIRE,
                             __HIP_MEMORY_SCOPE_AGENT) < NBLK) {
      __builtin_amdgcn_s_sleep(8);
    }
    __threadfence();
  }
  __syncthreads();
}

struct MegaArgs {
  const float *q, *k, *v;
  const float *wq, *bq, *wk, *bk, *wv, *bv, *wo, *bo;
  u16 *qb, *kb, *vb;
  u16 *Qh, *Kh, *Vh;
  u16 *wqb, *wkb, *wvb, *wob;
  u16 *Vt, *X;
  float *out, *attn;
  int *cnt;
};

// ---------------------------------------------------------------------------
// 128x64 GEMM tile (A[M,K] bf16 row-major, W[N,K] bf16 row-major, BK=32,
// 4 waves: wave w = rows w*32..+32).  2-phase dbuf.  LDS: 24KB at LDSp.
// MODE 0: head-split bf16 store with (x+bias)*scale; MODE 1: fp32 plain.
// ---------------------------------------------------------------------------
template <int MODE>
__device__ void gemm128x64(const u16* __restrict__ A, const u16* __restrict__ Wm,
                           const float* __restrict__ bias, u16* Yh, float* Yf,
                           float scale, int r0, int c0, char* LDSp, int tid) {
  char* As = LDSp;            // [2][128*32] bf16 = 2 x 8KB
  char* Bs = LDSp + 16384;    // [2][64*32]  bf16 = 2 x 4KB
  const int lane = tid & 63, w = tid >> 6;
  const int lr = lane & 15, lg = lane >> 4;
  f32x4 acc[2][4];
#pragma unroll
  for (int i = 0; i < 2; ++i)
#pragma unroll
    for (int j = 0; j < 4; ++j) acc[i][j] = (f32x4){0.f, 0.f, 0.f, 0.f};

  auto stage = [&](int k0, int buf) {
#pragma unroll
    for (int c = 0; c < 2; ++c) {
      int idx = tid + 256 * c;
      int row = idx >> 2, seg = idx & 3;
      gl_lds16(A + (size_t)(r0 + row) * DM + k0 + seg * 8,
               As + buf * 8192 + idx * 16);
    }
    {
      int row = tid >> 2, seg = tid & 3;
      gl_lds16(Wm + (size_t)(c0 + row) * DM + k0 + seg * 8,
               Bs + buf * 4096 + tid * 16);
    }
  };

  stage(0, 0);
  __syncthreads();
  int buf = 0;
#pragma unroll 1
  for (int t = 0; t < DM / 32; ++t) {
    if (t + 1 < DM / 32) stage((t + 1) * 32, buf ^ 1);
    bf16x8 aa[2], bb[4];
#pragma unroll
    for (int i = 0; i < 2; ++i) {
      int row = w * 32 + i * 16 + lr;
      aa[i] = *(const bf16x8*)(As + buf * 8192 + row * 64 + lg * 16);
    }
#pragma unroll
    for (int j = 0; j < 4; ++j) {
      int row2 = j * 16 + lr;
      bb[j] = *(const bf16x8*)(Bs + buf * 4096 + row2 * 64 + lg * 16);
    }
#pragma unroll
    for (int i = 0; i < 2; ++i)
#pragma unroll
      for (int j = 0; j < 4; ++j) acc[i][j] = MFMA16(aa[i], bb[j], acc[i][j]);
    __syncthreads();
    buf ^= 1;
  }
#pragma unroll
  for (int i = 0; i < 2; ++i)
#pragma unroll
    for (int j = 0; j < 4; ++j)
#pragma unroll
      for (int rg = 0; rg < 4; ++rg) {
        int row = r0 + w * 32 + i * 16 + lg * 4 + rg;
        int col = c0 + j * 16 + lr;
        if (MODE == 0) {
          float v = (acc[i][j][rg] + bias[col]) * scale;
          int bb2 = row >> 11, s = row & (SEQ - 1);
          int h = col >> 6, d = col & 63;
          Yh[((size_t)(bb2 * NH + h) * SEQ + s) * DKK + d] = f2bf(v);
        } else {
          Yf[(size_t)row * DM + col] = acc[i][j][rg] + bias[col];
        }
      }
}

// ---------------------------------------------------------------------------
// Fused flash + attn materialization for one (bh, qi) 64-row strip.
// LDS: Ks 2x8KB @0, Vs 2x8KB @16K, Ps 8KB @32K  (40KB total).
// ---------------------------------------------------------------------------
__device__ void flash64(const u16* __restrict__ Qb, const u16* __restrict__ Kb,
                        const u16* __restrict__ Vb, u16* __restrict__ X,
                        float* __restrict__ attb, int bh, int qi, char* LDSp,
                        int tid) {
  char* Ks = LDSp;            // [2][64*64] bf16
  char* Vs = LDSp + 16384;    // [2][64*64] bf16
  char* Ps = LDSp + 32768;    // [4][16*64] bf16 (per-wave 2KB)
  const int lane = tid & 63, w = tid >> 6;
  const int lr = lane & 15, lg = lane >> 4;
  const int q0 = qi * 64;
  const int qglob = q0 + w * 16 + lr;
  const int wmax = q0 + w * 16 + 15;
  const int nkv = qi + 1;

  bf16x8 frQ[2];
#pragma unroll
  for (int kc = 0; kc < 2; ++kc)
    frQ[kc] = *(const bf16x8*)(Qb + (size_t)qglob * DKK + kc * 32 + lg * 8);

  auto stageK = [&](int j, int buf) {
    const int kv0 = j * 64;
#pragma unroll
    for (int c = 0; c < 2; ++c) {
      int idx = tid + 256 * c;
      int row = idx >> 3, sq = idx & 7;
      int seg = sq ^ (row & 7);
      gl_lds16(Kb + (size_t)(kv0 + row) * DKK + seg * 8,
               Ks + buf * 8192 + idx * 16);
    }
  };
  auto stageV = [&](int j, int buf) {
    const int kv0 = j * 64;
#pragma unroll
    for (int c = 0; c < 2; ++c) {
      int idx = tid + 256 * c;
      int row = idx >> 3, sq = idx & 7;
      int seg = sq ^ (row & 7);
      gl_lds16(Vb + (size_t)row * SEQ + kv0 + seg * 8,
               Vs + buf * 8192 + idx * 16);
    }
  };

  // ---- Phase 1: rowsums ----
  float rs = 0.f;
  stageK(0, 0);
  VMCNT0();
  __builtin_amdgcn_s_barrier();
  SCHEDB();
  for (int j = 0; j < nkv; ++j) {
    const int buf = j & 1;
    const int kv0 = j * 64;
    if (j + 1 < nkv) stageK(j + 1, buf ^ 1);
    if (kv0 <= wmax) {
      __builtin_amdgcn_s_setprio(1);
#pragma unroll
      for (int ci = 0; ci < 4; ++ci) {
        bf16x8 aK[2];
#pragma unroll
        for (int kc = 0; kc < 2; ++kc) {
          int row = ci * 16 + lr;
          int qq = (kc * 4 + lg) ^ (row & 7);
          aK[kc] = *(const bf16x8*)(Ks + buf * 8192 + row * 128 + qq * 16);
        }
        f32x4 a = (f32x4){0.f, 0.f, 0.f, 0.f};
        a = MFMA16(aK[0], frQ[0], a);
        a = MFMA16(aK[1], frQ[1], a);
#pragma unroll
        for (int rg = 0; rg < 4; ++rg) {
          int kvglob = kv0 + ci * 16 + lg * 4 + rg;
          rs += (kvglob <= qglob) ? __expf(a[rg]) : 0.f;
        }
      }
      __builtin_amdgcn_s_setprio(0);
    }
    VMCNT0();
    __builtin_amdgcn_s_barrier();
    SCHEDB();
  }
  rs += __shfl_xor(rs, 16);
  rs += __shfl_xor(rs, 32);
  const float vinv = 1.f / rs;

  // ---- Phase 2: attn stores + PV ----
  f32x4 accO[4];
#pragma unroll
  for (int ci = 0; ci < 4; ++ci) accO[ci] = (f32x4){0.f, 0.f, 0.f, 0.f};

  stageK(0, 0);
  stageV(0, 0);
  VMCNT0();
  __builtin_amdgcn_s_barrier();
  SCHEDB();
  for (int j = 0; j < nkv; ++j) {
    const int buf = j & 1;
    const int kv0 = j * 64;
    if (j + 1 < nkv) {
      stageK(j + 1, buf ^ 1);
      stageV(j + 1, buf ^ 1);
    }
    float* orow = attb + (size_t)qglob * SEQ;
    if (kv0 <= wmax) {
      __builtin_amdgcn_s_setprio(1);
      f32x4 sf[4];
#pragma unroll
      for (int ci = 0; ci < 4; ++ci) {
        bf16x8 aK[2];
#pragma unroll
        for (int kc = 0; kc < 2; ++kc) {
          int row = ci * 16 + lr;
          int qq = (kc * 4 + lg) ^ (row & 7);
          aK[kc] = *(const bf16x8*)(Ks + buf * 8192 + row * 128 + qq * 16);
        }
        f32x4 a = (f32x4){0.f, 0.f, 0.f, 0.f};
        a = MFMA16(aK[0], frQ[0], a);
        a = MFMA16(aK[1], frQ[1], a);
        sf[ci] = a;
      }
#pragma unroll
      for (int ci = 0; ci < 4; ++ci) {
        float p[4];
#pragma unroll
        for (int rg = 0; rg < 4; ++rg) {
          int kvglob = kv0 + ci * 16 + lg * 4 + rg;
          p[rg] = (kvglob <= qglob) ? __expf(sf[ci][rg]) * vinv : 0.f;
        }
        f32x4 o = {p[0], p[1], p[2], p[3]};
        *(f32x4*)(orow + kv0 + ci * 16 + lg * 4) = o;
        u32 lo = (u32)f2bf(p[0]) | ((u32)f2bf(p[1]) << 16);
        u32 hi = (u32)f2bf(p[2]) | ((u32)f2bf(p[3]) << 16);
        int c16 = (ci * 2 + (lg >> 1)) ^ (lr & 7);
        char* dst = Ps + w * 2048 + lr * 128 + c16 * 16 + (lg & 1) * 8;
        *(uint2*)dst = (uint2){lo, hi};
      }
#pragma unroll
      for (int kvc = 0; kvc < 2; ++kvc) {
        int c16a = (kvc * 4 + lg) ^ (lr & 7);
        bf16x8 aP = *(const bf16x8*)(Ps + w * 2048 + lr * 128 + c16a * 16);
#pragma unroll
        for (int ci = 0; ci < 4; ++ci) {
          int row = ci * 16 + lr;
          int q2 = (kvc * 4 + lg) ^ (row & 7);
          bf16x8 bV = *(const bf16x8*)(Vs + buf * 8192 + row * 128 + q2 * 16);
          accO[ci] = MFMA16(aP, bV, accO[ci]);
        }
      }
      __builtin_amdgcn_s_setprio(0);
    } else {
      const f32x4 z = {0.f, 0.f, 0.f, 0.f};
#pragma unroll
      for (int ci = 0; ci < 4; ++ci)
        *(f32x4*)(orow + kv0 + ci * 16 + lg * 4) = z;
    }
    VMCNT0();
    __builtin_amdgcn_s_barrier();
    SCHEDB();
  }

  // zero tail beyond the diagonal
  {
    const f32x4 z = {0.f, 0.f, 0.f, 0.f};
    float* orow = attb + (size_t)qglob * SEQ;
    for (int j = nkv; j < SEQ / 64; ++j) {
      const int kv0 = j * 64;
#pragma unroll
      for (int ci = 0; ci < 4; ++ci)
        *(f32x4*)(orow + kv0 + ci * 16 + lg * 4) = z;
    }
  }

  // X store (normalized O)
  const int b = bh >> 4, h = bh & (NH - 1);
#pragma unroll
  for (int ci = 0; ci < 4; ++ci)
#pragma unroll
    for (int rg = 0; rg < 4; ++rg) {
      int srow = q0 + w * 16 + lg * 4 + rg;
      int col = h * DKK + ci * 16 + lr;
      X[((size_t)(b * SEQ + srow)) * DM + col] = f2bf(accO[ci][rg]);
    }
}

// ---------------------------------------------------------------------------
// The mega-kernel: cvt -> proj -> transpose -> flash+attn -> out, with
// software grid barriers (all 512 blocks co-resident by launch_bounds).
// ---------------------------------------------------------------------------
__global__ __launch_bounds__(256, 2) void mega(MegaArgs a) {
  __shared__ __align__(16) char LDS[40 * 1024];
  const int tid = threadIdx.x, bid = (int)blockIdx.x;

  // ---- S0: fp32 -> bf16 convert (exact grid-stride, 32 iters) ----
  {
    const int base = bid * 256 + tid;
#pragma unroll 4
    for (int it = 0; it < 32; ++it) {
      int i = base + it * (NBLK * 256);
      const float* in;
      u16* outp;
      int loc;
      if (i < 3145728) {
        int t = i >> 20;
        loc = i & 1048575;
        in = (t == 0) ? a.q : (t == 1) ? a.k : a.v;
        outp = (t == 0) ? a.qb : (t == 1) ? a.kb : a.vb;
      } else {
        int j2 = i - 3145728;
        int t = j2 >> 18;
        loc = j2 & 262143;
        in = (t == 0) ? a.wq : (t == 1) ? a.wk : (t == 2) ? a.wv : a.wo;
        outp = (t == 0) ? a.wqb : (t == 1) ? a.wkb : (t == 2) ? a.wvb : a.wob;
      }
      float4 vv = ((const float4*)in)[loc];
      ushort4 o;
      o.x = f2bf(vv.x); o.y = f2bf(vv.y); o.z = f2bf(vv.z); o.w = f2bf(vv.w);
      ((ushort4*)outp)[loc] = o;
    }
  }
  gbar(a.cnt, 0);

  // ---- S1: Q/K/V projections, 1536 jobs (3 gemms x 16c x 32r), 3/block ----
  for (int s = 0; s < 3; ++s) {
    int job = bid + s * NBLK;
    int g = job >> 9;          // 0..2
    int jl = job & 511;
    int ct = jl & 15, rt = jl >> 4;
    const u16* A = (g == 0) ? a.qb : (g == 1) ? a.kb : a.vb;
    const u16* Wm = (g == 0) ? a.wqb : (g == 1) ? a.wkb : a.wvb;
    const float* bias = (g == 0) ? a.bq : (g == 1) ? a.bk : a.bv;
    u16* Y = (g == 0) ? a.Qh : (g == 1) ? a.Kh : a.Vh;
    float scale = (g == 0) ? 0.125f : 1.0f;
    gemm128x64<0>(A, Wm, bias, Y, nullptr, scale, rt * 128, ct * 64, LDS, tid);
    __syncthreads();
  }
  gbar(a.cnt, 1);

  // ---- S2: V transpose, 1024 jobs (32 st x 32 bh), 2/block ----
  for (int s = 0; s < 2; ++s) {
    int job = bid + s * NBLK;
    int st = job & 31, bh = job >> 5;
    const u16* src = a.Vh + ((size_t)bh * SEQ + st * 64) * DKK;
    u16* dst = a.Vt + (size_t)bh * DKK * SEQ + st * 64;
    u16(*T)[68] = (u16(*)[68])LDS;
#pragma unroll
    for (int c = 0; c < 4; ++c) {
      int idx = tid + 256 * c;
      int r = idx >> 4, seg = idx & 15;
      ushort4 v = *(const ushort4*)(src + r * 64 + seg * 4);
      *(ushort4*)&T[r][seg * 4] = v;
    }
    __syncthreads();
#pragma unroll
    for (int c = 0; c < 4; ++c) {
      int idx = tid + 256 * c;
      int d = idx >> 4, sseg = idx & 15;
      ushort4 o;
      o.x = T[sseg * 4 + 0][d]; o.y = T[sseg * 4 + 1][d];
      o.z = T[sseg * 4 + 2][d]; o.w = T[sseg * 4 + 3][d];
      *(ushort4*)(dst + (size_t)d * SEQ + sseg * 4) = o;
    }
    __syncthreads();
  }
  gbar(a.cnt, 2);

  // ---- S3: fused flash+attn, 1024 jobs paired (qi, 31-qi): uniform load ----
  {
    const int iq = bid & 15, bh = bid >> 4;
    const u16* Qb = a.Qh + (size_t)bh * SEQ * DKK;
    const u16* Kb = a.Kh + (size_t)bh * SEQ * DKK;
    const u16* Vb = a.Vt + (size_t)bh * DKK * SEQ;
    float* attb = a.attn + (size_t)bh * SEQ * SEQ;
#pragma unroll 1
    for (int pp = 0; pp < 2; ++pp) {
      int qi = pp ? (31 - iq) : iq;
      flash64(Qb, Kb, Vb, a.X, attb, bh, qi, LDS, tid);
      __syncthreads();
    }
  }
  gbar(a.cnt, 3);

  // ---- S4: output projection, 512 jobs (16c x 32r), 1/block ----
  {
    int ct = bid & 15, rt = bid >> 4;
    gemm128x64<1>(a.X, a.wob, a.bo, nullptr, a.out, 1.0f, rt * 128, ct * 64,
                  LDS, tid);
  }
}

// ---------------------------------------------------------------------------
extern "C" void kernel_launch(void* const* d_in, const int* in_sizes, int n_in,
                              void* d_out, int out_size, void* d_ws,
                              size_t ws_size, hipStream_t stream) {
  MegaArgs ma;
  ma.q = (const float*)d_in[0];
  ma.k = (const float*)d_in[1];
  ma.v = (const float*)d_in[2];
  // d_in[3] = causal mask (structure used directly)
  ma.wq = (const float*)d_in[4];
  ma.bq = (const float*)d_in[5];
  ma.wk = (const float*)d_in[6];
  ma.bk = (const float*)d_in[7];
  ma.wv = (const float*)d_in[8];
  ma.bv = (const float*)d_in[9];
  ma.wo = (const float*)d_in[10];
  ma.bo = (const float*)d_in[11];

  float* out = (float*)d_out;                 // [B,S,DM] fp32
  ma.out = out;
  ma.attn = out + (size_t)NB * SEQ * DM;      // [B,H,S,S] fp32

  const size_t MB = 1u << 20;
  char* ws = (char*)d_ws;
  ma.qb = (u16*)(ws);             // 8MB
  ma.kb = (u16*)(ws + 8 * MB);    // 8MB
  ma.vb = (u16*)(ws + 16 * MB);   // 8MB; reused as X
  ma.Qh = (u16*)(ws + 24 * MB);   // 8MB [bh][s][d] (pre-scaled by 1/8)
  ma.Kh = (u16*)(ws + 32 * MB);   // 8MB
  ma.Vh = (u16*)(ws + 40 * MB);   // 8MB
  ma.wqb = (u16*)(ws + 48 * MB);  // 2MB each
  ma.wkb = (u16*)(ws + 50 * MB);
  ma.wvb = (u16*)(ws + 52 * MB);
  ma.wob = (u16*)(ws + 54 * MB);
  ma.Vt = ma.qb;                  // qb dead after S1
  ma.X = ma.vb;                   // vb dead after S1
  ma.cnt = (int*)(ws + 56 * MB);  // grid-barrier counters

  // zero barrier counters (graph-legal; re-executed on every replay)
  hipMemsetAsync(ma.cnt, 0, 64, stream);

  mega<<<dim3(NBLK), dim3(256), 0, stream>>>(ma);
}

// Round 13
// 278.361 us; speedup vs baseline: 2.6460x; 2.6460x over previous
//
#include <hip/hip_runtime.h>
#include <hip/hip_bf16.h>

typedef unsigned short u16;
typedef unsigned int u32;
typedef __attribute__((ext_vector_type(8))) short bf16x8;
typedef __attribute__((ext_vector_type(4))) float f32x4;

#define SEQ 2048
#define DM 1024
#define NH 16
#define DKK 64
#define NB 2

__device__ __forceinline__ u16 f2bf(float f) {
  union { float f; u32 u; } x; x.f = f;
  u32 r = x.u + 0x7FFFu + ((x.u >> 16) & 1u);
  return (u16)(r >> 16);
}

__device__ __forceinline__ void gl_lds16(const void* g, void* l) {
  __builtin_amdgcn_global_load_lds(
      (const __attribute__((address_space(1))) u32*)g,
      (__attribute__((address_space(3))) u32*)l, 16, 0, 0);
}

#define MFMA16(a, b, c) __builtin_amdgcn_mfma_f32_16x16x32_bf16(a, b, c, 0, 0, 0)
#define VMCNT0() asm volatile("s_waitcnt vmcnt(0)" ::: "memory")
#define SCHEDB() __builtin_amdgcn_sched_barrier(0)

// ---------------------------------------------------------------------------
// fp32 -> bf16 bulk convert, all 7 tensors in one launch (blockIdx.y picks).
// ---------------------------------------------------------------------------
struct CvtArgs {
  const float* in[7];
  u16* out[7];
  int n4[7];
};

__global__ __launch_bounds__(256) void cvt_all(CvtArgs a) {
  const int y = blockIdx.y;
  const float* in = a.in[y];
  u16* out = a.out[y];
  const int n4 = a.n4[y];
  int i = blockIdx.x * 256 + threadIdx.x;
  if (i >= n4) return;
  float4 v = ((const float4*)in)[i];
  ushort4 o;
  o.x = f2bf(v.x); o.y = f2bf(v.y); o.z = f2bf(v.z); o.w = f2bf(v.w);
  ((ushort4*)out)[i] = o;
}

// ---------------------------------------------------------------------------
// Fused Q/K/V projection GEMMs (blockIdx.z selects which).
// C = A * W^T, + bias, * scale, scatter bf16 to head-split [bh][s][d].
// 128x128 tile, BK=32, 4 waves.  (r4-exact: single-buffer, 2 barriers/K-step.)
// ---------------------------------------------------------------------------
struct ProjArgs {
  const u16* A;
  const u16* W;
  const float* bias;
  u16* Y;
  float scale;
};

__global__ __launch_bounds__(256) void proj_qkv(ProjArgs a0, ProjArgs a1,
                                                ProjArgs a2) {
  ProjArgs pa = (blockIdx.z == 0) ? a0 : (blockIdx.z == 1) ? a1 : a2;
  const int K = DM;
  __shared__ __align__(16) u16 As[128 * 32];
  __shared__ __align__(16) u16 Bs[128 * 32];
  const int tid = threadIdx.x, lane = tid & 63, w = tid >> 6;
  const int lr = lane & 15, lg = lane >> 4;
  const int wr = w >> 1, wc = w & 1;
  const int r0 = blockIdx.x * 128, c0 = blockIdx.y * 128;
  f32x4 acc[4][4];
#pragma unroll
  for (int i = 0; i < 4; ++i)
#pragma unroll
    for (int j = 0; j < 4; ++j) acc[i][j] = (f32x4){0.f, 0.f, 0.f, 0.f};

  for (int k0 = 0; k0 < K; k0 += 32) {
    if (k0) __syncthreads();
#pragma unroll
    for (int c = 0; c < 2; ++c) {
      int idx = tid + 256 * c;
      int row = idx >> 2, seg = idx & 3;
      gl_lds16(pa.A + (size_t)(r0 + row) * K + k0 + seg * 8,
               (char*)As + idx * 16);
      gl_lds16(pa.W + (size_t)(c0 + row) * K + k0 + seg * 8,
               (char*)Bs + idx * 16);
    }
    __syncthreads();
    bf16x8 a[4], b[4];
#pragma unroll
    for (int i = 0; i < 4; ++i) {
      int row = wr * 64 + i * 16 + lr;
      a[i] = *(const bf16x8*)((const char*)As + row * 64 + lg * 16);
    }
#pragma unroll
    for (int j = 0; j < 4; ++j) {
      int row = wc * 64 + j * 16 + lr;
      b[j] = *(const bf16x8*)((const char*)Bs + row * 64 + lg * 16);
    }
#pragma unroll
    for (int i = 0; i < 4; ++i)
#pragma unroll
      for (int j = 0; j < 4; ++j) acc[i][j] = MFMA16(a[i], b[j], acc[i][j]);
  }
#pragma unroll
  for (int i = 0; i < 4; ++i)
#pragma unroll
    for (int j = 0; j < 4; ++j)
#pragma unroll
      for (int rg = 0; rg < 4; ++rg) {
        int row = r0 + wr * 64 + i * 16 + lg * 4 + rg;
        int col = c0 + wc * 64 + j * 16 + lr;
        float v = (acc[i][j][rg] + pa.bias[col]) * pa.scale;
        int bb = row >> 11, s = row & (SEQ - 1), h = col >> 6, d = col & 63;
        pa.Y[((size_t)(bb * NH + h) * SEQ + s) * DKK + d] = f2bf(v);
      }
}

// ---------------------------------------------------------------------------
// Output projection: Y(fp32) = X(bf16)*Wo^T + bo.  Same structure.
// ---------------------------------------------------------------------------
__global__ __launch_bounds__(256) void mm_out(const u16* __restrict__ A,
                                              const u16* __restrict__ W,
                                              const float* __restrict__ bias,
                                              float* __restrict__ Y) {
  const int K = DM;
  __shared__ __align__(16) u16 As[128 * 32];
  __shared__ __align__(16) u16 Bs[128 * 32];
  const int tid = threadIdx.x, lane = tid & 63, w = tid >> 6;
  const int lr = lane & 15, lg = lane >> 4;
  const int wr = w >> 1, wc = w & 1;
  const int r0 = blockIdx.x * 128, c0 = blockIdx.y * 128;
  f32x4 acc[4][4];
#pragma unroll
  for (int i = 0; i < 4; ++i)
#pragma unroll
    for (int j = 0; j < 4; ++j) acc[i][j] = (f32x4){0.f, 0.f, 0.f, 0.f};

  for (int k0 = 0; k0 < K; k0 += 32) {
    if (k0) __syncthreads();
#pragma unroll
    for (int c = 0; c < 2; ++c) {
      int idx = tid + 256 * c;
      int row = idx >> 2, seg = idx & 3;
      gl_lds16(A + (size_t)(r0 + row) * K + k0 + seg * 8, (char*)As + idx * 16);
      gl_lds16(W + (size_t)(c0 + row) * K + k0 + seg * 8, (char*)Bs + idx * 16);
    }
    __syncthreads();
    bf16x8 a[4], b[4];
#pragma unroll
    for (int i = 0; i < 4; ++i) {
      int row = wr * 64 + i * 16 + lr;
      a[i] = *(const bf16x8*)((const char*)As + row * 64 + lg * 16);
    }
#pragma unroll
    for (int j = 0; j < 4; ++j) {
      int row = wc * 64 + j * 16 + lr;
      b[j] = *(const bf16x8*)((const char*)Bs + row * 64 + lg * 16);
    }
#pragma unroll
    for (int i = 0; i < 4; ++i)
#pragma unroll
      for (int j = 0; j < 4; ++j) acc[i][j] = MFMA16(a[i], b[j], acc[i][j]);
  }
#pragma unroll
  for (int i = 0; i < 4; ++i)
#pragma unroll
    for (int j = 0; j < 4; ++j)
#pragma unroll
      for (int rg = 0; rg < 4; ++rg) {
        int row = r0 + wr * 64 + i * 16 + lg * 4 + rg;
        int col = c0 + wc * 64 + j * 16 + lr;
        Y[(size_t)row * DM + col] = acc[i][j][rg] + bias[col];
      }
}

// ---------------------------------------------------------------------------
// Vh[bh][s][d] -> Vt[bh][d][s]  (64x64 tiles through LDS)
// ---------------------------------------------------------------------------
__global__ __launch_bounds__(256) void transpose_v(const u16* __restrict__ Vh,
                                                   u16* __restrict__ Vt) {
  const int st = blockIdx.x, bh = blockIdx.y;
  const u16* src = Vh + ((size_t)bh * SEQ + st * 64) * DKK;
  u16* dst = Vt + (size_t)bh * DKK * SEQ + st * 64;
  __shared__ u16 T[64][68];
  const int tid = threadIdx.x;
#pragma unroll
  for (int c = 0; c < 4; ++c) {
    int idx = tid + 256 * c;
    int r = idx >> 4, seg = idx & 15;
    ushort4 v = *(const ushort4*)(src + r * 64 + seg * 4);
    *(ushort4*)&T[r][seg * 4] = v;
  }
  __syncthreads();
#pragma unroll
  for (int c = 0; c < 4; ++c) {
    int idx = tid + 256 * c;
    int d = idx >> 4, sseg = idx & 15;
    ushort4 o;
    o.x = T[sseg * 4 + 0][d]; o.y = T[sseg * 4 + 1][d];
    o.z = T[sseg * 4 + 2][d]; o.w = T[sseg * 4 + 3][d];
    *(ushort4*)(dst + (size_t)d * SEQ + sseg * 4) = o;
  }
}

// ---------------------------------------------------------------------------
// Flash forward, swapped-QK^T + packed-P + 2-phase dbuf pipeline (r4-exact).
// ---------------------------------------------------------------------------
__global__ __launch_bounds__(256) void flash_fwd(const u16* __restrict__ Qh,
                                                 const u16* __restrict__ Kh,
                                                 const u16* __restrict__ Vt,
                                                 u16* __restrict__ X,
                                                 float* __restrict__ linv) {
  const int lin = (int)(blockIdx.y * gridDim.x + blockIdx.x);
  const int nwg = (int)(gridDim.x * gridDim.y);
  const int swz = (lin & 7) * (nwg >> 3) + (lin >> 3);
  const int qi = (int)gridDim.x - 1 - (swz & 15);  // heavy tiles first
  const int bh = swz >> 4;
  const int q0 = qi * 128;
  const u16* Qb = Qh + (size_t)bh * SEQ * DKK;
  const u16* Kb = Kh + (size_t)bh * SEQ * DKK;
  const u16* Vb = Vt + (size_t)bh * DKK * SEQ;
  const int tid = threadIdx.x, lane = tid & 63, w = tid >> 6;
  const int lr = lane & 15, lg = lane >> 4;

  __shared__ __align__(16) u16 Ks[2][64 * 64];  // [kv][d] swizzled 16B chunks
  __shared__ __align__(16) u16 Vs[2][64 * 64];  // [d][kv] swizzled
  __shared__ __align__(16) u16 Ps[4 * 32 * 64]; // per-wave [q=32][kv=64]

  bf16x8 frQ[2][2];
#pragma unroll
  for (int ri = 0; ri < 2; ++ri)
#pragma unroll
    for (int kc = 0; kc < 2; ++kc) {
      int r = q0 + w * 32 + ri * 16 + lr;
      frQ[ri][kc] = *(const bf16x8*)(Qb + (size_t)r * DKK + kc * 32 + lg * 8);
    }

  f32x4 accO[2][4];
  float rs[2] = {0.f, 0.f};
#pragma unroll
  for (int ri = 0; ri < 2; ++ri)
#pragma unroll
    for (int ci = 0; ci < 4; ++ci) accO[ri][ci] = (f32x4){0.f, 0.f, 0.f, 0.f};

  const int wmax = q0 + w * 32 + 31;
  const int nkv = (qi + 1) * 2;

  auto stage = [&](int j, int buf) {
    const int kv0 = j * 64;
#pragma unroll
    for (int c = 0; c < 2; ++c) {
      int idx = tid + 256 * c;
      int row = idx >> 3, sq = idx & 7;
      int seg = sq ^ (row & 7);
      gl_lds16(Kb + (size_t)(kv0 + row) * DKK + seg * 8,
               (char*)Ks[buf] + idx * 16);
      gl_lds16(Vb + (size_t)row * SEQ + kv0 + seg * 8,
               (char*)Vs[buf] + idx * 16);
    }
  };

  stage(0, 0);
  VMCNT0();
  __builtin_amdgcn_s_barrier();
  SCHEDB();

  for (int j = 0; j < nkv; ++j) {
    const int buf = j & 1;
    const int kv0 = j * 64;
    if (j + 1 < nkv) stage(j + 1, buf ^ 1);  // overlaps compute below

    if (kv0 <= wmax) {
      __builtin_amdgcn_s_setprio(1);
      f32x4 sf[4][2];
#pragma unroll
      for (int ci = 0; ci < 4; ++ci) {
        bf16x8 aK[2];
#pragma unroll
        for (int kc = 0; kc < 2; ++kc) {
          int row = ci * 16 + lr;
          int q = (kc * 4 + lg) ^ (row & 7);
          aK[kc] = *(const bf16x8*)((const char*)Ks[buf] + row * 128 + q * 16);
        }
#pragma unroll
        for (int ri = 0; ri < 2; ++ri) {
          f32x4 a = (f32x4){0.f, 0.f, 0.f, 0.f};
          a = MFMA16(aK[0], frQ[ri][0], a);
          a = MFMA16(aK[1], frQ[ri][1], a);
          sf[ci][ri] = a;
        }
      }
#pragma unroll
      for (int ri = 0; ri < 2; ++ri) {
        const int qglob = q0 + w * 32 + ri * 16 + lr;
        const int qlrow = ri * 16 + lr;
#pragma unroll
        for (int ci = 0; ci < 4; ++ci) {
          float p[4];
#pragma unroll
          for (int rg = 0; rg < 4; ++rg) {
            int kvglob = kv0 + ci * 16 + lg * 4 + rg;
            p[rg] = (kvglob <= qglob) ? __expf(sf[ci][ri][rg]) : 0.f;
          }
          rs[ri] += (p[0] + p[1]) + (p[2] + p[3]);
          u32 lo = (u32)f2bf(p[0]) | ((u32)f2bf(p[1]) << 16);
          u32 hi = (u32)f2bf(p[2]) | ((u32)f2bf(p[3]) << 16);
          int c16 = (ci * 2 + (lg >> 1)) ^ (lr & 7);
          char* dst = (char*)Ps + w * 4096 + qlrow * 128 + c16 * 16 +
                      (lg & 1) * 8;
          *(uint2*)dst = (uint2){lo, hi};
        }
      }
#pragma unroll
      for (int kvc = 0; kvc < 2; ++kvc) {
        bf16x8 aP[2];
#pragma unroll
        for (int ri = 0; ri < 2; ++ri) {
          int qlrow = ri * 16 + lr;
          int c16 = (kvc * 4 + lg) ^ (lr & 7);
          aP[ri] = *(const bf16x8*)((const char*)Ps + w * 4096 + qlrow * 128 +
                                    c16 * 16);
        }
#pragma unroll
        for (int ci = 0; ci < 4; ++ci) {
          int row = ci * 16 + lr;
          int q2 = (kvc * 4 + lg) ^ (row & 7);
          bf16x8 bV =
              *(const bf16x8*)((const char*)Vs[buf] + row * 128 + q2 * 16);
#pragma unroll
          for (int ri = 0; ri < 2; ++ri)
            accO[ri][ci] = MFMA16(aP[ri], bV, accO[ri][ci]);
        }
      }
      __builtin_amdgcn_s_setprio(0);
    }
    VMCNT0();
    __builtin_amdgcn_s_barrier();
    SCHEDB();
  }

  const int b = bh >> 4, h = bh & (NH - 1);
  float vinv[2];
#pragma unroll
  for (int ri = 0; ri < 2; ++ri) {
    float v = rs[ri];
    v += __shfl_xor(v, 16);
    v += __shfl_xor(v, 32);
    float iv = 1.f / v;
    vinv[ri] = iv;
    int qglob = q0 + w * 32 + ri * 16 + lr;
    if (lg == 0) linv[(size_t)bh * SEQ + qglob] = iv;
  }
  float inv_[2][4];
#pragma unroll
  for (int ri = 0; ri < 2; ++ri)
#pragma unroll
    for (int rg = 0; rg < 4; ++rg)
      inv_[ri][rg] = __shfl(vinv[ri], lg * 4 + rg);

#pragma unroll
  for (int ri = 0; ri < 2; ++ri)
#pragma unroll
    for (int ci = 0; ci < 4; ++ci)
#pragma unroll
      for (int rg = 0; rg < 4; ++rg) {
        int srow = q0 + w * 32 + ri * 16 + lg * 4 + rg;
        int col = h * DKK + ci * 16 + lr;
        X[((size_t)(b * SEQ + srow)) * DM + col] =
            f2bf(accO[ri][ci][rg] * inv_[ri][rg]);
      }
}

// ---------------------------------------------------------------------------
// Materialize attn: recompute S tile, write exp(s)*linv (fp32) or zeros.
// 64x64 tiles; zero tiles (ct>rt) are pure float4 stores.
// ---------------------------------------------------------------------------
__global__ __launch_bounds__(256) void attn_mat(const u16* __restrict__ Qh,
                                                const u16* __restrict__ Kh,
                                                const float* __restrict__ linv,
                                                float* __restrict__ attn) {
  const int rt = blockIdx.x, ct = blockIdx.y, bh = blockIdx.z;
  float* out = attn + (size_t)bh * SEQ * SEQ;
  const int tid = threadIdx.x;
  if (ct > rt) {
    float4 z = {0.f, 0.f, 0.f, 0.f};
#pragma unroll
    for (int c = 0; c < 4; ++c) {
      int idx = tid + 256 * c;
      int row = idx >> 4, c4 = idx & 15;
      *(float4*)(out + (size_t)(rt * 64 + row) * SEQ + ct * 64 + c4 * 4) = z;
    }
    return;
  }
  const u16* Qb = Qh + (size_t)bh * SEQ * DKK;
  const u16* Kb = Kh + (size_t)bh * SEQ * DKK;
  __shared__ __align__(16) u16 Qs[64 * 64];
  __shared__ __align__(16) u16 Ks2[64 * 64];
  const int lane = tid & 63, w = tid >> 6, lr = lane & 15, lg = lane >> 4;
#pragma unroll
  for (int c = 0; c < 2; ++c) {
    int idx = tid + 256 * c;
    int row = idx >> 3, sq = idx & 7, seg = sq ^ (row & 7);
    gl_lds16(Qb + (size_t)(rt * 64 + row) * DKK + seg * 8,
             (char*)Qs + idx * 16);
    gl_lds16(Kb + (size_t)(ct * 64 + row) * DKK + seg * 8,
             (char*)Ks2 + idx * 16);
  }
  __syncthreads();
  bf16x8 aQ[2];
#pragma unroll
  for (int kc = 0; kc < 2; ++kc) {
    int row = w * 16 + lr;
    int q = (kc * 4 + lg) ^ (row & 7);
    aQ[kc] = *(const bf16x8*)((const char*)Qs + row * 128 + q * 16);
  }
  float lrow[4];
#pragma unroll
  for (int rg = 0; rg < 4; ++rg)
    lrow[rg] = linv[(size_t)bh * SEQ + rt * 64 + w * 16 + lg * 4 + rg];
  const bool full = (ct < rt);
#pragma unroll
  for (int ci = 0; ci < 4; ++ci) {
    bf16x8 bK[2];
#pragma unroll
    for (int kc = 0; kc < 2; ++kc) {
      int row = ci * 16 + lr;
      int q = (kc * 4 + lg) ^ (row & 7);
      bK[kc] = *(const bf16x8*)((const char*)Ks2 + row * 128 + q * 16);
    }
    f32x4 a = (f32x4){0.f, 0.f, 0.f, 0.f};
    a = MFMA16(aQ[0], bK[0], a);
    a = MFMA16(aQ[1], bK[1], a);
#pragma unroll
    for (int rg = 0; rg < 4; ++rg) {
      int row = rt * 64 + w * 16 + lg * 4 + rg;
      int col = ct * 64 + ci * 16 + lr;
      float v = (full || col <= row) ? __expf(a[rg]) * lrow[rg] : 0.f;
      out[(size_t)row * SEQ + col] = v;
    }
  }
}

// ---------------------------------------------------------------------------
extern "C" void kernel_launch(void* const* d_in, const int* in_sizes, int n_in,
                              void* d_out, int out_size, void* d_ws,
                              size_t ws_size, hipStream_t stream) {
  const float* q = (const float*)d_in[0];
  const float* k = (const float*)d_in[1];
  const float* v = (const float*)d_in[2];
  // d_in[3] = causal mask (structure used directly)
  const float* w_q = (const float*)d_in[4];
  const float* b_q = (const float*)d_in[5];
  const float* w_k = (const float*)d_in[6];
  const float* b_k = (const float*)d_in[7];
  const float* w_v = (const float*)d_in[8];
  const float* b_v = (const float*)d_in[9];
  const float* w_o = (const float*)d_in[10];
  const float* b_o = (const float*)d_in[11];

  float* out = (float*)d_out;                 // [B,S,DM] fp32
  float* attn = out + (size_t)NB * SEQ * DM;  // [B,H,S,S] fp32

  const size_t MB = 1u << 20;
  char* ws = (char*)d_ws;
  u16* qb = (u16*)(ws);             // 8MB; reused as Vt after Q-proj
  u16* kb = (u16*)(ws + 8 * MB);    // 8MB
  u16* vb = (u16*)(ws + 16 * MB);   // 8MB; reused as X after V-proj
  u16* Qh = (u16*)(ws + 24 * MB);   // 8MB [bh][s][d] (pre-scaled by 1/8)
  u16* Kh = (u16*)(ws + 32 * MB);   // 8MB [bh][s][d]
  u16* Vh = (u16*)(ws + 40 * MB);   // 8MB [bh][s][d] (dead after transpose)
  u16* wqb = (u16*)(ws + 48 * MB);  // 2MB each
  u16* wkb = (u16*)(ws + 50 * MB);
  u16* wvb = (u16*)(ws + 52 * MB);
  u16* wob = (u16*)(ws + 54 * MB);
  float* linv = (float*)(ws + 56 * MB);  // 256KB
  u16* Vt = qb;                          // [bh][d][s]
  u16* X = vb;                           // [b*s][DM] bf16

  dim3 blk(256);
  const int n4_qkv = NB * SEQ * DM / 4;  // 1,048,576
  const int n4_w = DM * DM / 4;          // 262,144

  CvtArgs ca;
  ca.in[0] = q;   ca.out[0] = qb;  ca.n4[0] = n4_qkv;
  ca.in[1] = k;   ca.out[1] = kb;  ca.n4[1] = n4_qkv;
  ca.in[2] = v;   ca.out[2] = vb;  ca.n4[2] = n4_qkv;
  ca.in[3] = w_q; ca.out[3] = wqb; ca.n4[3] = n4_w;
  ca.in[4] = w_k; ca.out[4] = wkb; ca.n4[4] = n4_w;
  ca.in[5] = w_v; ca.out[5] = wvb; ca.n4[5] = n4_w;
  ca.in[6] = w_o; ca.out[6] = wob; ca.n4[6] = n4_w;
  cvt_all<<<dim3((n4_qkv + 255) / 256, 7), blk, 0, stream>>>(ca);

  ProjArgs aq = {qb, wqb, b_q, Qh, 0.125f};  // fold 1/sqrt(64) into Q
  ProjArgs ak = {kb, wkb, b_k, Kh, 1.0f};
  ProjArgs av = {vb, wvb, b_v, Vh, 1.0f};
  proj_qkv<<<dim3(NB * SEQ / 128, DM / 128, 3), blk, 0, stream>>>(aq, ak, av);

  transpose_v<<<dim3(SEQ / 64, NB * NH), blk, 0, stream>>>(Vh, Vt);

  flash_fwd<<<dim3(SEQ / 128, NB * NH), blk, 0, stream>>>(Qh, Kh, Vt, X, linv);

  mm_out<<<dim3(NB * SEQ / 128, DM / 128), blk, 0, stream>>>(X, wob, b_o, out);

  attn_mat<<<dim3(SEQ / 64, SEQ / 64, NB * NH), blk, 0, stream>>>(Qh, Kh, linv,
                                                                  attn);
}